// Round 8
// baseline (703.322 us; speedup 1.0000x reference)
//
#include <hip/hip_runtime.h>

// ---------------------------------------------------------------------------
// Swin block on MI355X. Inputs/outputs f32; internal activations/weights bf16
// (u16), f32 accumulate in MFMA. Round 10: LN2 fused into the proj GEMM
// (proj_ln: 128x256 tile, full row per block, cross-wave LN via LDS partials;
// writes out f32 + z bf16 in one pass -- removes the ln2 dispatch and its
// 103MB re-read). 4 transpose launches merged into one. gemm_bt (BK=64,
// XOR-swizzled), attn (swizzled), fused_mlp (R2 pipeline) unchanged from R7.
// ---------------------------------------------------------------------------

typedef unsigned short u16;
typedef __attribute__((ext_vector_type(8))) short bfrag8;     // 8 bf16 = 4 VGPRs
typedef __attribute__((ext_vector_type(8))) unsigned short u16x8;
typedef __attribute__((ext_vector_type(4))) float f32x4;

#define WS_TOK 49
#define C_DIM 256
#define M_ROWS 100352        // 32 * 56 * 56
#define N_WIN 2048           // 32 * 64
#define SCALE_Q 0.17677669529663689f

#if defined(__has_builtin)
#  if __has_builtin(__builtin_amdgcn_global_load_lds)
#    define HAVE_GLL 1
#  endif
#endif
#ifndef HAVE_GLL
#  define HAVE_GLL 0
#endif

__device__ __forceinline__ float u2f(u16 u) {
    union { unsigned int i; float f; } c; c.i = ((unsigned int)u) << 16; return c.f;
}
__device__ __forceinline__ u16 f2u(float f) {
    union { float f; unsigned int i; } c; c.f = f;
    unsigned int i = c.i;
    return (u16)((i + 0x7fffu + ((i >> 16) & 1u)) >> 16);   // RNE
}
__device__ __forceinline__ int regionOf(int h) {           // shift-mask region id
    return h < 49 ? 0 : (h < 53 ? 1 : 2);                  // 0:-7 / -7:-3 / -3:
}
__device__ __forceinline__ float gelu_tanh(float v) {
    const float y = 0.79788456080286536f * (v + 0.044715f * v * v * v);
    const float e = __expf(2.f * y);                        // tanh via one exp
    const float t = 1.f - 2.f / (e + 1.f);
    return 0.5f * v * (1.f + t);
}

__device__ __forceinline__ void g2l16(const u16* g, u16* l) {
#if HAVE_GLL
    __builtin_amdgcn_global_load_lds((const __attribute__((address_space(1))) void*)g,
                                     (__attribute__((address_space(3))) void*)l, 16, 0, 0);
#else
    *(bfrag8*)l = *(const bfrag8*)g;
#endif
}

// ------------- all weight transposes + f32->bf16 cast, one launch ----------
__global__ void transpose_all(const float* __restrict__ qkv_w,
                              const float* __restrict__ proj_w,
                              const float* __restrict__ w1,
                              const float* __restrict__ w2,
                              u16* __restrict__ qkvT, u16* __restrict__ projT,
                              u16* __restrict__ w1T, u16* __restrict__ w2T) {
    const int bid = blockIdx.x;
    const float* in; u16* outp; int R, Ccols, base;
    if (bid < 768)       { in = qkv_w;  outp = qkvT;  R = 256;  Ccols = 768;  base = bid; }
    else if (bid < 1024) { in = proj_w; outp = projT; R = 256;  Ccols = 256;  base = bid - 768; }
    else if (bid < 2048) { in = w1;     outp = w1T;   R = 256;  Ccols = 1024; base = bid - 1024; }
    else                 { in = w2;     outp = w2T;   R = 1024; Ccols = 256;  base = bid - 2048; }
    const int i = base * 256 + threadIdx.x;
    if (i < R * Ccols) {
        const int r = i / Ccols, c = i - r * Ccols;
        outp[(size_t)c * R + r] = f2u(in[i]);
    }
}

// ------------- LayerNorm f32->bf16 (mode0: +shift+window gather) -----------
__global__ __launch_bounds__(256) void ln_kernel(const float* __restrict__ xin,
                                                 const float* __restrict__ g,
                                                 const float* __restrict__ b,
                                                 u16* __restrict__ out, int mode) {
    const int w = threadIdx.x >> 6, lane = threadIdx.x & 63;
    const int r = blockIdx.x * 4 + w;   // destination row (windowed order in mode0)
    int s = r;
    if (mode == 0) {
        const int win = r / WS_TOK, tok = r - win * WS_TOK;
        const int b_ = win >> 6, w64 = win & 63;
        const int wr = w64 >> 3, wc = w64 & 7;
        const int th = tok / 7, tw = tok - th * 7;
        int hh = wr * 7 + th + 3; if (hh >= 56) hh -= 56;   // roll(-3) gather
        int ww = wc * 7 + tw + 3; if (ww >= 56) ww -= 56;
        s = b_ * 3136 + hh * 56 + ww;
    }
    const float4 u = *(const float4*)(xin + (size_t)s * C_DIM + lane * 4);
    float f0 = u.x, f1 = u.y, f2 = u.z, f3 = u.w;
    float s1 = f0 + f1 + f2 + f3;
    float s2 = f0 * f0 + f1 * f1 + f2 * f2 + f3 * f3;
#pragma unroll
    for (int off = 32; off; off >>= 1) {
        s1 += __shfl_xor(s1, off, 64);
        s2 += __shfl_xor(s2, off, 64);
    }
    const float mu = s1 * (1.f / 256.f);
    const float rs = rsqrtf(s2 * (1.f / 256.f) - mu * mu + 1e-5f);
    const float4 ug = *(const float4*)(g + lane * 4);
    const float4 ub = *(const float4*)(b + lane * 4);
    ushort4 o;
    o.x = f2u((f0 - mu) * rs * ug.x + ub.x);
    o.y = f2u((f1 - mu) * rs * ug.y + ub.y);
    o.z = f2u((f2 - mu) * rs * ug.z + ub.z);
    o.w = f2u((f3 - mu) * rs * ug.w + ub.w);
    *(ushort4*)(out + (size_t)r * C_DIM + lane * 4) = o;
}

// ------------------------------- GEMM (qkv) --------------------------------
// C(M,N) = A(M,K) @ Bt(N,K)^T ; 128x128 tile, BK=64, 4 waves in 2x2.
// 32 MFMA per barrier-pair. LDS 32KB XOR-swizzled (verified R7).
// EPI 0: qkv scatter (bf16)
template <int KD, int ND, int NY, int EPI>
__global__ __launch_bounds__(256) void gemm_bt(const u16* __restrict__ A,
                                               const u16* __restrict__ Bt,
                                               const float* __restrict__ bias,
                                               u16* __restrict__ o0,
                                               u16* __restrict__ o1,
                                               u16* __restrict__ o2,
                                               float* __restrict__ fo,
                                               const float* __restrict__ res) {
    __shared__ __align__(16) char pool[32768];      // As(16K)+Bs(16K) / Ts
    u16* As = (u16*)pool;
    u16* Bs = (u16*)(pool + 16384);
    const int tid = threadIdx.x;
    const int bid = blockIdx.x;
    const int m0 = (bid / NY) * 128;
    const int n0 = (bid % NY) * 128;
    const int wid = tid >> 6, lane = tid & 63;
    const int wy = wid >> 1, wx = wid & 1;
    const int l15 = lane & 15, lsel = lane >> 4;

    f32x4 acc[4][4] = {};
    const u16* Ag = A + (size_t)m0 * KD;
    const u16* Bg = Bt + (size_t)n0 * KD;

    for (int k0 = 0; k0 < KD; k0 += 64) {
#pragma unroll
        for (int p = 0; p < 4; ++p) {               // 128 rows x 8 segs of 8 u16
            const int idx = p * 256 + tid;
            const int row = idx >> 3, s = idx & 7;
            const int so = (s ^ (row & 7)) << 3;    // source-preswizzled seg
            g2l16(Ag + (size_t)row * KD + k0 + so, As + idx * 8);
            g2l16(Bg + (size_t)row * KD + k0 + so, Bs + idx * 8);
        }
        __syncthreads();
#pragma unroll
        for (int kh = 0; kh < 2; ++kh) {
            bfrag8 af[4], bfv[4];
#pragma unroll
            for (int m = 0; m < 4; ++m) {
                const int r = wy * 64 + m * 16 + l15;
                af[m] = *(const bfrag8*)(As + r * 64 +
                         ((kh * 32 + lsel * 8) ^ ((r & 7) << 3)));
            }
#pragma unroll
            for (int n = 0; n < 4; ++n) {
                const int r = wx * 64 + n * 16 + l15;
                bfv[n] = *(const bfrag8*)(Bs + r * 64 +
                          ((kh * 32 + lsel * 8) ^ ((r & 7) << 3)));
            }
#pragma unroll
            for (int m = 0; m < 4; ++m)
#pragma unroll
                for (int n = 0; n < 4; ++n)
                    acc[m][n] = __builtin_amdgcn_mfma_f32_16x16x32_bf16(
                        af[m], bfv[n], acc[m][n], 0, 0, 0);
        }
        __syncthreads();
    }

    // ---------------- epilogue: per-wave LDS transpose ----------------
    float* Ts = (float*)pool + wid * (16 * 68);     // 4352 B per wave
    const int r  = lane >> 2;
    const int cg = (lane & 3) << 4;

#pragma unroll
    for (int m = 0; m < 4; ++m) {
#pragma unroll
        for (int n = 0; n < 4; ++n)
#pragma unroll
            for (int reg = 0; reg < 4; ++reg)
                Ts[(lsel * 4 + reg) * 68 + n * 16 + l15] = acc[m][n][reg];
        float vals[16];
#pragma unroll
        for (int j = 0; j < 4; ++j)
            *(f32x4*)(vals + 4 * j) = *(const f32x4*)(Ts + r * 68 + cg + 4 * j);

        const int gr  = m0 + wy * 64 + m * 16 + r;
        const int gc0 = n0 + wx * 64 + cg;
        float bias16[16];
#pragma unroll
        for (int j = 0; j < 4; ++j)
            *(f32x4*)(bias16 + 4 * j) = *(const f32x4*)(bias + gc0 + 4 * j);

        if (EPI == 0) {
            const int win = gr / WS_TOK, tok = gr - win * WS_TOK;
            const int part = gc0 >> 8, head = (gc0 >> 5) & 7, hd = gc0 & 31;
            u16* dst = (part == 0) ? o0 : (part == 1) ? o1 : o2;
            const float sc = (part == 0) ? SCALE_Q : 1.f;
            const size_t di = (size_t)win * 8 * (WS_TOK * 32) + (size_t)tok * 32 +
                              (size_t)head * (WS_TOK * 32) + hd;
            u16x8 pk[2];
#pragma unroll
            for (int j = 0; j < 16; ++j)
                ((u16*)pk)[j] = f2u((vals[j] + bias16[j]) * sc);
            *(u16x8*)(dst + di)     = pk[0];
            *(u16x8*)(dst + di + 8) = pk[1];
        }
    }
}

// ----------------- proj GEMM + residual + LN2 fused (new) ------------------
// out = x + ao@projT^T + proj_b (window-reverse scatter), z = LN2(out) bf16.
// Tile 128 rows x 256 cols (full row per block -> LN feasible). 4 waves 2x2,
// wave tile 64x128, acc[4][8]. BK=64, XOR-swizzled staging (As 16K, Bs 32K).
// Epilogue: per-wave LDS transpose -> lane owns 32 contiguous cols of a row;
// row LN stats = 32-elem local sum + shfl over 4 lanes + LDS partial combine
// across the 2 wx waves (1 barrier per 16-row strip).
__global__ __launch_bounds__(256, 2) void proj_ln(const u16* __restrict__ A,
                                                  const u16* __restrict__ Bt,
                                                  const float* __restrict__ bias,
                                                  const float* __restrict__ res,
                                                  const float* __restrict__ g2,
                                                  const float* __restrict__ b2,
                                                  float* __restrict__ out,
                                                  u16* __restrict__ zout) {
    __shared__ __align__(16) char pool[49152];      // As 16K + Bs 32K / Ts+part
    u16* As = (u16*)pool;
    u16* Bs = (u16*)(pool + 16384);
    const int tid = threadIdx.x;
    const int m0 = blockIdx.x * 128;
    const int wid = tid >> 6, lane = tid & 63;
    const int wy = wid >> 1, wx = wid & 1;
    const int l15 = lane & 15, lsel = lane >> 4;

    f32x4 acc[4][8] = {};
    const u16* Ag = A + (size_t)m0 * 256;

    for (int k0 = 0; k0 < 256; k0 += 64) {
#pragma unroll
        for (int p = 0; p < 4; ++p) {               // As: 128 rows x 8 segs
            const int idx = p * 256 + tid;
            const int row = idx >> 3, s = idx & 7;
            g2l16(Ag + (size_t)row * 256 + k0 + ((s ^ (row & 7)) << 3),
                  As + idx * 8);
        }
#pragma unroll
        for (int p = 0; p < 8; ++p) {               // Bs: 256 rows x 8 segs
            const int idx = p * 256 + tid;
            const int row = idx >> 3, s = idx & 7;
            g2l16(Bt + (size_t)row * 256 + k0 + ((s ^ (row & 7)) << 3),
                  Bs + idx * 8);
        }
        __syncthreads();
#pragma unroll
        for (int kh = 0; kh < 2; ++kh) {
            bfrag8 af[4], bf[8];
#pragma unroll
            for (int m = 0; m < 4; ++m) {
                const int r = wy * 64 + m * 16 + l15;
                af[m] = *(const bfrag8*)(As + r * 64 +
                         ((kh * 32 + lsel * 8) ^ ((r & 7) << 3)));
            }
#pragma unroll
            for (int n = 0; n < 8; ++n) {
                const int r = wx * 128 + n * 16 + l15;
                bf[n] = *(const bfrag8*)(Bs + r * 64 +
                         ((kh * 32 + lsel * 8) ^ ((r & 7) << 3)));
            }
#pragma unroll
            for (int m = 0; m < 4; ++m)
#pragma unroll
                for (int n = 0; n < 8; ++n)
                    acc[m][n] = __builtin_amdgcn_mfma_f32_16x16x32_bf16(
                        af[m], bf[n], acc[m][n], 0, 0, 0);
        }
        __syncthreads();
    }

    // ---------------- epilogue: transpose + residual + LN ----------------
    float* Ts = (float*)pool + wid * (16 * 132);    // 8448 B per wave (33792 tot)
    float* part = (float*)(pool + 33792);           // [128 rows][2 wx][2] = 2 KB
    const int r4 = lane >> 2;                       // row within 16-row strip
    const int cg = (lane & 3) << 5;                 // 32-col group in wave half

#pragma unroll
    for (int m = 0; m < 4; ++m) {
#pragma unroll
        for (int n = 0; n < 8; ++n)
#pragma unroll
            for (int reg = 0; reg < 4; ++reg)
                Ts[(lsel * 4 + reg) * 132 + n * 16 + l15] = acc[m][n][reg];
        // wave-internal write->read: compiler inserts lgkmcnt wait
        float vals[32];
#pragma unroll
        for (int j = 0; j < 8; ++j)
            *(f32x4*)(vals + 4 * j) = *(const f32x4*)(Ts + r4 * 132 + cg + 4 * j);

        const int gr  = m0 + wy * 64 + m * 16 + r4;
        const int gc0 = wx * 128 + cg;
        const int win = gr / WS_TOK, tok = gr - win * WS_TOK;
        const int b_ = win >> 6, w64 = win & 63;
        const int wr = w64 >> 3, wc = w64 & 7;
        const int th = tok / 7, tw = tok - th * 7;
        int hh = wr * 7 + th + 3; if (hh >= 56) hh -= 56;  // roll(+3) scatter
        int ww = wc * 7 + tw + 3; if (ww >= 56) ww -= 56;
        const size_t rowbase = ((size_t)b_ * 3136 + hh * 56 + ww) * C_DIM;

        float s1 = 0.f, s2 = 0.f;
#pragma unroll
        for (int j = 0; j < 8; ++j) {
            f32x4 rr = *(const f32x4*)(res + rowbase + gc0 + 4 * j);
            f32x4 b4 = *(const f32x4*)(bias + gc0 + 4 * j);
#pragma unroll
            for (int e = 0; e < 4; ++e) {
                const float v = rr[e] + vals[4 * j + e] + b4[e];
                vals[4 * j + e] = v;
                s1 += v; s2 += v * v;
            }
        }
        s1 += __shfl_xor(s1, 1, 64); s2 += __shfl_xor(s2, 1, 64);
        s1 += __shfl_xor(s1, 2, 64); s2 += __shfl_xor(s2, 2, 64);
        const int prow = wy * 64 + m * 16 + r4;
        if ((lane & 3) == 0) {
            part[(prow * 2 + wx) * 2 + 0] = s1;
            part[(prow * 2 + wx) * 2 + 1] = s2;
        }
        __syncthreads();                            // both wx partials landed
        const float t1 = part[(prow * 2 + 0) * 2 + 0] + part[(prow * 2 + 1) * 2 + 0];
        const float t2 = part[(prow * 2 + 0) * 2 + 1] + part[(prow * 2 + 1) * 2 + 1];
        const float mu = t1 * (1.f / 256.f);
        const float rs = rsqrtf(t2 * (1.f / 256.f) - mu * mu + 1e-5f);
        u16x8 pk[4];
#pragma unroll
        for (int j = 0; j < 8; ++j) {
            f32x4 v = *(const f32x4*)(vals + 4 * j);
            *(f32x4*)(out + rowbase + gc0 + 4 * j) = v;   // residual out (f32)
            f32x4 gg = *(const f32x4*)(g2 + gc0 + 4 * j);
            f32x4 bb = *(const f32x4*)(b2 + gc0 + 4 * j);
#pragma unroll
            for (int e = 0; e < 4; ++e)
                ((u16*)pk)[4 * j + e] = f2u((v[e] - mu) * rs * gg[e] + bb[e]);
        }
        u16* zd = zout + rowbase + gc0;
#pragma unroll
        for (int j = 0; j < 4; ++j)
            *(u16x8*)(zd + 8 * j) = pk[j];
        __syncthreads();                            // part/Ts safe for next strip
    }
}

// --------------------------- fused MLP (R2-verified) -----------------------
// out += GELU(z @ w1T^T + b1) @ w2T^T + b2; h never leaves LDS.
// M-tile 64 rows, 4 waves (2x2). z persistent in LDS. Stage next 16KB tile
// into alternate buffer BEFORE the MFMAs, one __syncthreads per step.
// LDS 80KB -> 2 blocks/CU.
__device__ __forceinline__ void stage_w1t(const u16* __restrict__ w1T, u16* dst,
                                          int kc, int k0, int tid) {
#pragma unroll
    for (int p = 0; p < 4; ++p) {                   // [128 hcols][64 k] = 16KB
        const int i = p * 256 + tid;
        const int row = i >> 3, s = i & 7;
        g2l16(w1T + (size_t)(kc * 128 + row) * 256 + k0 + ((s ^ (row & 7)) << 3),
              dst + i * 8);
    }
}
__device__ __forceinline__ void stage_w2t(const u16* __restrict__ w2T, u16* dst,
                                          int kc, int bs, int tid) {
#pragma unroll
    for (int p = 0; p < 4; ++p) {                   // [256 outcols][32 k] = 16KB
        const int i = p * 256 + tid;
        const int row = i >> 2, s = i & 3;
        g2l16(w2T + (size_t)row * 1024 + kc * 128 + bs * 32 +
                  ((s ^ ((row >> 1) & 3)) << 3),
              dst + i * 8);
    }
}

__global__ __launch_bounds__(256, 2) void fused_mlp(const u16* __restrict__ z,
                                                    const u16* __restrict__ w1T,
                                                    const float* __restrict__ b1,
                                                    const u16* __restrict__ w2T,
                                                    const float* __restrict__ b2,
                                                    float* __restrict__ out) {
    __shared__ __align__(16) u16 pool[40960];       // 80 KB
    u16* zS  = pool;                                // [0,16384)  32 KB persistent
    u16* wb0 = pool + 16384;                        // 16 KB stage buffer A
    u16* wb1 = pool + 24576;                        // 16 KB stage buffer B
    u16* hc  = pool + 32768;                        // 16 KB h-chunk
    const int tid = threadIdx.x;
    const int wid = tid >> 6, lane = tid & 63;
    const int wy = wid >> 1, wx = wid & 1;
    const int l15 = lane & 15, lsel = lane >> 4;
    const int m0 = blockIdx.x * 64;

    // one-time z stage: [64 rows][256 k], source pre-swizzled (seg ^ row&7)
#pragma unroll
    for (int p = 0; p < 8; ++p) {
        const int i = p * 256 + tid;
        const int row = i >> 5, s = i & 31;
        g2l16(z + (size_t)(m0 + row) * 256 + ((s ^ (row & 7)) << 3), zS + i * 8);
    }
    stage_w1t(w1T, wb0, 0, 0, tid);                 // prologue: first w1 tile
    __syncthreads();

    f32x4 acc2[2][8] = {};

    for (int kc = 0; kc < 8; ++kc) {
        float b1v[4];
#pragma unroll
        for (int n = 0; n < 4; ++n)
            b1v[n] = b1[kc * 128 + wx * 64 + n * 16 + l15];

        f32x4 acc1[2][4] = {};
        // ---------------- 4 A-steps: acc1 += zS @ w1-tile -----------------
#pragma unroll
        for (int ks = 0; ks < 4; ++ks) {
            u16* wc = (ks & 1) ? wb1 : wb0;
            u16* wn = (ks & 1) ? wb0 : wb1;
            if (ks < 3) stage_w1t(w1T, wn, kc, (ks + 1) * 64, tid);
            else        stage_w2t(w2T, wn, kc, 0, tid);
#pragma unroll
            for (int sub = 0; sub < 2; ++sub) {
                bfrag8 af[2], bf[4];
#pragma unroll
                for (int m = 0; m < 2; ++m) {
                    const int r = wy * 32 + m * 16 + l15;
                    af[m] = *(const bfrag8*)(zS + r * 256 +
                             ((ks * 64 + sub * 32 + lsel * 8) ^ ((r & 7) << 3)));
                }
#pragma unroll
                for (int n = 0; n < 4; ++n) {
                    const int r = wx * 64 + n * 16 + l15;
                    bf[n] = *(const bfrag8*)(wc + r * 64 +
                             ((sub * 32 + lsel * 8) ^ ((r & 7) << 3)));
                }
#pragma unroll
                for (int m = 0; m < 2; ++m)
#pragma unroll
                    for (int n = 0; n < 4; ++n)
                        acc1[m][n] = __builtin_amdgcn_mfma_f32_16x16x32_bf16(
                            af[m], bf[n], acc1[m][n], 0, 0, 0);
            }
            if (ks == 3) {                          // GELU -> hc (swizzled bf16)
#pragma unroll
                for (int m = 0; m < 2; ++m)
#pragma unroll
                    for (int n = 0; n < 4; ++n)
#pragma unroll
                        for (int reg = 0; reg < 4; ++reg) {
                            const int rh = wy * 32 + m * 16 + lsel * 4 + reg;
                            const int ch = wx * 64 + n * 16 + l15;
                            hc[rh * 128 + (ch ^ ((rh & 15) << 3))] =
                                f2u(gelu_tanh(acc1[m][n][reg] + b1v[n]));
                        }
            }
            __syncthreads();
        }
        // ---------------- 4 B-steps: acc2 += hc @ w2-tile -----------------
#pragma unroll
        for (int bs = 0; bs < 4; ++bs) {
            u16* wc = (bs & 1) ? wb1 : wb0;
            u16* wn = (bs & 1) ? wb0 : wb1;
            if (bs < 3)      stage_w2t(w2T, wn, kc, bs + 1, tid);
            else if (kc < 7) stage_w1t(w1T, wn, kc + 1, 0, tid);
            bfrag8 a2[2], bb[8];
#pragma unroll
            for (int m = 0; m < 2; ++m) {
                const int r = wy * 32 + m * 16 + l15;
                a2[m] = *(const bfrag8*)(hc + r * 128 +
                         ((bs * 32 + lsel * 8) ^ ((r & 15) << 3)));
            }
#pragma unroll
            for (int n = 0; n < 8; ++n) {
                const int r = wx * 128 + n * 16 + l15;
                bb[n] = *(const bfrag8*)(wc + r * 32 +
                         ((lsel * 8) ^ (((r >> 1) & 3) << 3)));
            }
#pragma unroll
            for (int m = 0; m < 2; ++m)
#pragma unroll
                for (int n = 0; n < 8; ++n)
                    acc2[m][n] = __builtin_amdgcn_mfma_f32_16x16x32_bf16(
                        a2[m], bb[n], acc2[m][n], 0, 0, 0);
            __syncthreads();
        }
    }

    // ---------------- final epilogue: out += acc2 + b2 (in place) ---------
    float b2v[8];
#pragma unroll
    for (int n = 0; n < 8; ++n)
        b2v[n] = b2[wx * 128 + n * 16 + l15];
#pragma unroll
    for (int m = 0; m < 2; ++m)
#pragma unroll
        for (int reg = 0; reg < 4; ++reg) {
            const int row = m0 + wy * 32 + m * 16 + lsel * 4 + reg;
#pragma unroll
            for (int n = 0; n < 8; ++n) {
                const size_t di = (size_t)row * 256 + wx * 128 + n * 16 + l15;
                out[di] += acc2[m][n][reg] + b2v[n];
            }
        }
}

// ------------------------------ attention ----------------------------------
// 4 waves per 256-thread block, one (window,head) per wave, wave-private LDS
// (no barriers). 49 padded to 64. Vt and Pb XOR-swizzled (verified R7).
__global__ __launch_bounds__(256) void attn_kernel(const u16* __restrict__ q,
                                                   const u16* __restrict__ k,
                                                   const u16* __restrict__ v,
                                                   const float* __restrict__ relb,
                                                   u16* __restrict__ ao) {
    __shared__ __align__(16) u16 PbAll[4][64 * 64];
    __shared__ __align__(16) u16 VtAll[4][32 * 64];
    const int wid = threadIdx.x >> 6;
    const int lane = threadIdx.x & 63;
    u16* Pb = PbAll[wid];
    u16* Vt = VtAll[wid];
    const int bid = blockIdx.x * 4 + wid;
    const int head = bid & 7, win = bid >> 3;
    const int w64 = win & 63;
    const int wr = w64 >> 3, wc = w64 & 7;
    const int l15 = lane & 15, lsel = lane >> 4;
    const size_t base = (size_t)bid * (WS_TOK * 32);
    const u16* qb = q + base;
    const u16* kb = k + base;
    const u16* vb = v + base;

    // stage V transposed: Vt[dim][tok^((dim&7)<<3)], zero-pad tok 49..63
    for (int idx = lane; idx < WS_TOK * 32; idx += 64) {
        const int tok = idx >> 5, dim = idx & 31;
        Vt[dim * 64 + (tok ^ ((dim & 7) << 3))] = vb[idx];
    }
    for (int i = lane; i < 32 * 15; i += 64) {
        const int dim = i / 15, tok = 49 + (i - dim * 15);
        Vt[dim * 64 + (tok ^ ((dim & 7) << 3))] = 0;
    }

    bfrag8 qf[4], kf[4];
#pragma unroll
    for (int m = 0; m < 4; ++m) {
        int tok = m * 16 + l15; if (tok > 48) tok = 48;
        qf[m] = *(const bfrag8*)(qb + tok * 32 + lsel * 8);
    }
#pragma unroll
    for (int n = 0; n < 4; ++n) {
        int tok = n * 16 + l15; if (tok > 48) tok = 48;
        kf[n] = *(const bfrag8*)(kb + tok * 32 + lsel * 8);
    }
    f32x4 S[4][4] = {};
#pragma unroll
    for (int m = 0; m < 4; ++m)
#pragma unroll
        for (int n = 0; n < 4; ++n)
            S[m][n] = __builtin_amdgcn_mfma_f32_16x16x32_bf16(qf[m], kf[n], S[m][n], 0, 0, 0);

    // bias + shift-mask + row softmax, write normalized P to LDS (swizzled)
#pragma unroll
    for (int m = 0; m < 4; ++m) {
#pragma unroll
        for (int reg = 0; reg < 4; ++reg) {
            const int row = m * 16 + lsel * 4 + reg;
            const int rowc = row > 48 ? 48 : row;
            const int ih = rowc / 7, iw = rowc - ih * 7;
            const int ri = regionOf(wr * 7 + ih) * 3 + regionOf(wc * 7 + iw);
            float sv[4];
#pragma unroll
            for (int n = 0; n < 4; ++n) {
                const int col = n * 16 + l15;
                float val = S[m][n][reg];
                if (col > 48) {
                    val = -1e30f;
                } else {
                    const int jh = col / 7, jw = col - jh * 7;
                    val += relb[((ih - jh + 6) * 13 + (iw - jw + 6)) * 8 + head];
                    const int rj = regionOf(wr * 7 + jh) * 3 + regionOf(wc * 7 + jw);
                    if (ri != rj) val -= 100.f;
                }
                sv[n] = val;
            }
            float mx = fmaxf(fmaxf(sv[0], sv[1]), fmaxf(sv[2], sv[3]));
#pragma unroll
            for (int off = 1; off < 16; off <<= 1) mx = fmaxf(mx, __shfl_xor(mx, off, 64));
            float p[4], sum = 0.f;
#pragma unroll
            for (int n = 0; n < 4; ++n) { p[n] = __expf(sv[n] - mx); sum += p[n]; }
#pragma unroll
            for (int off = 1; off < 16; off <<= 1) sum += __shfl_xor(sum, off, 64);
            const float inv = 1.f / sum;
#pragma unroll
            for (int n = 0; n < 4; ++n)
                Pb[row * 64 + ((n * 16 + l15) ^ ((row & 7) << 3))] = f2u(p[n] * inv);
        }
    }
    // wave-private LDS: no barrier needed

    // O = P V
    f32x4 O[4][2] = {};
    bfrag8 vf[2][2];
#pragma unroll
    for (int n = 0; n < 2; ++n) {
        const int r = n * 16 + l15;
        vf[n][0] = *(const bfrag8*)(Vt + r * 64 + ((lsel * 8) ^ ((r & 7) << 3)));
        vf[n][1] = *(const bfrag8*)(Vt + r * 64 + ((32 + lsel * 8) ^ ((r & 7) << 3)));
    }
#pragma unroll
    for (int m = 0; m < 4; ++m) {
        const int r = m * 16 + l15;
        const bfrag8 pf0 = *(const bfrag8*)(Pb + r * 64 +
                            ((lsel * 8) ^ ((r & 7) << 3)));
        const bfrag8 pf1 = *(const bfrag8*)(Pb + r * 64 +
                            ((32 + lsel * 8) ^ ((r & 7) << 3)));
#pragma unroll
        for (int n = 0; n < 2; ++n) {
            O[m][n] = __builtin_amdgcn_mfma_f32_16x16x32_bf16(pf0, vf[n][0], O[m][n], 0, 0, 0);
            O[m][n] = __builtin_amdgcn_mfma_f32_16x16x32_bf16(pf1, vf[n][1], O[m][n], 0, 0, 0);
        }
    }
    const size_t aob = (size_t)win * (WS_TOK * C_DIM) + head * 32;
#pragma unroll
    for (int m = 0; m < 4; ++m) {
#pragma unroll
        for (int reg = 0; reg < 4; ++reg) {
            const int row = m * 16 + lsel * 4 + reg;
            if (row < WS_TOK) {
#pragma unroll
                for (int n = 0; n < 2; ++n)
                    ao[aob + (size_t)row * C_DIM + n * 16 + l15] = f2u(O[m][n][reg]);
            }
        }
    }
}

// ------------------------------ launcher -----------------------------------
extern "C" void kernel_launch(void* const* d_in, const int* in_sizes, int n_in,
                              void* d_out, int out_size, void* d_ws, size_t ws_size,
                              hipStream_t stream) {
    (void)in_sizes; (void)n_in; (void)out_size; (void)ws_size;
    const float* x      = (const float*)d_in[0];
    const float* qkv_w  = (const float*)d_in[1];
    const float* qkv_b  = (const float*)d_in[2];
    const float* proj_w = (const float*)d_in[3];
    const float* proj_b = (const float*)d_in[4];
    const float* relb   = (const float*)d_in[5];
    const float* ln1g   = (const float*)d_in[6];
    const float* ln1b   = (const float*)d_in[7];
    const float* ln2g   = (const float*)d_in[8];
    const float* ln2b   = (const float*)d_in[9];
    const float* w1     = (const float*)d_in[10];
    const float* b1     = (const float*)d_in[11];
    const float* w2     = (const float*)d_in[12];
    const float* b2     = (const float*)d_in[13];
    float* out = (float*)d_out;

    const size_t SZ = (size_t)M_ROWS * C_DIM;      // 25,690,112 elements
    u16* wsu  = (u16*)d_ws;
    u16* xw   = wsu;                                // LN1-windowed input (bf16)
    u16* qq   = wsu + SZ;
    u16* kk   = wsu + 2 * SZ;
    u16* vv   = wsu + 3 * SZ;
    u16* ao   = wsu + 4 * SZ;
    u16* z    = xw;                                 // reuse (xw dead after QKV)
    u16* qkvT = wsu + 5 * SZ;
    u16* projT = qkvT + 256 * 768;
    u16* w1T  = projT + 256 * 256;
    u16* w2T  = w1T + 256 * 1024;

    transpose_all<<<3072, 256, 0, stream>>>(qkv_w, proj_w, w1, w2,
                                            qkvT, projT, w1T, w2T);

    ln_kernel<<<M_ROWS / 4, 256, 0, stream>>>(x, ln1g, ln1b, xw, 0);

    gemm_bt<256, 768, 6, 0><<<784 * 6, 256, 0, stream>>>(xw, qkvT, qkv_b,
                                                         qq, kk, vv, nullptr, nullptr);

    attn_kernel<<<N_WIN * 8 / 4, 256, 0, stream>>>(qq, kk, vv, relb, ao);

    proj_ln<<<784, 256, 0, stream>>>(ao, projT, proj_b, x, ln2g, ln2b, out, z);

    fused_mlp<<<M_ROWS / 64, 256, 0, stream>>>(z, w1T, b1, w2T, b2, out);
}

// Round 9
// 665.383 us; speedup vs baseline: 1.0570x; 1.0570x over previous
//
#include <hip/hip_runtime.h>

// ---------------------------------------------------------------------------
// Swin block on MI355X. Inputs/outputs f32; internal activations/weights bf16
// (u16), f32 accumulate in MFMA. Round 11: revert proj_ln fusion (R8: -51us
// loss -- barrier-heavy epilogue) back to R7's proj gemm + ln2 pair (674us
// best). Keep transpose_all merge. attn: V staging vectorized (25 scalar 2B
// global loads/lane -> 4x 16B loads + ds_write scatter).
// ---------------------------------------------------------------------------

typedef unsigned short u16;
typedef __attribute__((ext_vector_type(8))) short bfrag8;     // 8 bf16 = 4 VGPRs
typedef __attribute__((ext_vector_type(8))) unsigned short u16x8;
typedef __attribute__((ext_vector_type(4))) float f32x4;

#define WS_TOK 49
#define C_DIM 256
#define M_ROWS 100352        // 32 * 56 * 56
#define N_WIN 2048           // 32 * 64
#define SCALE_Q 0.17677669529663689f

#if defined(__has_builtin)
#  if __has_builtin(__builtin_amdgcn_global_load_lds)
#    define HAVE_GLL 1
#  endif
#endif
#ifndef HAVE_GLL
#  define HAVE_GLL 0
#endif

__device__ __forceinline__ float u2f(u16 u) {
    union { unsigned int i; float f; } c; c.i = ((unsigned int)u) << 16; return c.f;
}
__device__ __forceinline__ u16 f2u(float f) {
    union { float f; unsigned int i; } c; c.f = f;
    unsigned int i = c.i;
    return (u16)((i + 0x7fffu + ((i >> 16) & 1u)) >> 16);   // RNE
}
__device__ __forceinline__ int regionOf(int h) {           // shift-mask region id
    return h < 49 ? 0 : (h < 53 ? 1 : 2);                  // 0:-7 / -7:-3 / -3:
}
__device__ __forceinline__ float gelu_tanh(float v) {
    const float y = 0.79788456080286536f * (v + 0.044715f * v * v * v);
    const float e = __expf(2.f * y);                        // tanh via one exp
    const float t = 1.f - 2.f / (e + 1.f);
    return 0.5f * v * (1.f + t);
}

__device__ __forceinline__ void g2l16(const u16* g, u16* l) {
#if HAVE_GLL
    __builtin_amdgcn_global_load_lds((const __attribute__((address_space(1))) void*)g,
                                     (__attribute__((address_space(3))) void*)l, 16, 0, 0);
#else
    *(bfrag8*)l = *(const bfrag8*)g;
#endif
}

// ------------- all weight transposes + f32->bf16 cast, one launch ----------
__global__ void transpose_all(const float* __restrict__ qkv_w,
                              const float* __restrict__ proj_w,
                              const float* __restrict__ w1,
                              const float* __restrict__ w2,
                              u16* __restrict__ qkvT, u16* __restrict__ projT,
                              u16* __restrict__ w1T, u16* __restrict__ w2T) {
    const int bid = blockIdx.x;
    const float* in; u16* outp; int R, Ccols, base;
    if (bid < 768)       { in = qkv_w;  outp = qkvT;  R = 256;  Ccols = 768;  base = bid; }
    else if (bid < 1024) { in = proj_w; outp = projT; R = 256;  Ccols = 256;  base = bid - 768; }
    else if (bid < 2048) { in = w1;     outp = w1T;   R = 256;  Ccols = 1024; base = bid - 1024; }
    else                 { in = w2;     outp = w2T;   R = 1024; Ccols = 256;  base = bid - 2048; }
    const int i = base * 256 + threadIdx.x;
    if (i < R * Ccols) {
        const int r = i / Ccols, c = i - r * Ccols;
        outp[(size_t)c * R + r] = f2u(in[i]);
    }
}

// ------------- LayerNorm f32->bf16 (mode0: +shift+window gather) -----------
__global__ __launch_bounds__(256) void ln_kernel(const float* __restrict__ xin,
                                                 const float* __restrict__ g,
                                                 const float* __restrict__ b,
                                                 u16* __restrict__ out, int mode) {
    const int w = threadIdx.x >> 6, lane = threadIdx.x & 63;
    const int r = blockIdx.x * 4 + w;   // destination row (windowed order in mode0)
    int s = r;
    if (mode == 0) {
        const int win = r / WS_TOK, tok = r - win * WS_TOK;
        const int b_ = win >> 6, w64 = win & 63;
        const int wr = w64 >> 3, wc = w64 & 7;
        const int th = tok / 7, tw = tok - th * 7;
        int hh = wr * 7 + th + 3; if (hh >= 56) hh -= 56;   // roll(-3) gather
        int ww = wc * 7 + tw + 3; if (ww >= 56) ww -= 56;
        s = b_ * 3136 + hh * 56 + ww;
    }
    const float4 u = *(const float4*)(xin + (size_t)s * C_DIM + lane * 4);
    float f0 = u.x, f1 = u.y, f2 = u.z, f3 = u.w;
    float s1 = f0 + f1 + f2 + f3;
    float s2 = f0 * f0 + f1 * f1 + f2 * f2 + f3 * f3;
#pragma unroll
    for (int off = 32; off; off >>= 1) {
        s1 += __shfl_xor(s1, off, 64);
        s2 += __shfl_xor(s2, off, 64);
    }
    const float mu = s1 * (1.f / 256.f);
    const float rs = rsqrtf(s2 * (1.f / 256.f) - mu * mu + 1e-5f);
    const float4 ug = *(const float4*)(g + lane * 4);
    const float4 ub = *(const float4*)(b + lane * 4);
    ushort4 o;
    o.x = f2u((f0 - mu) * rs * ug.x + ub.x);
    o.y = f2u((f1 - mu) * rs * ug.y + ub.y);
    o.z = f2u((f2 - mu) * rs * ug.z + ub.z);
    o.w = f2u((f3 - mu) * rs * ug.w + ub.w);
    *(ushort4*)(out + (size_t)r * C_DIM + lane * 4) = o;
}

// ------------------------------- GEMM --------------------------------------
// C(M,N) = A(M,K) @ Bt(N,K)^T ; 128x128 tile, BK=64, 4 waves in 2x2.
// 32 MFMA per barrier-pair. LDS 32KB XOR-swizzled (verified R7).
// EPI 0: qkv scatter (bf16)  1: proj+reverse+residual (f32)
template <int KD, int ND, int NY, int EPI>
__global__ __launch_bounds__(256) void gemm_bt(const u16* __restrict__ A,
                                               const u16* __restrict__ Bt,
                                               const float* __restrict__ bias,
                                               u16* __restrict__ o0,
                                               u16* __restrict__ o1,
                                               u16* __restrict__ o2,
                                               float* __restrict__ fo,
                                               const float* __restrict__ res) {
    __shared__ __align__(16) char pool[32768];      // As(16K)+Bs(16K) / Ts
    u16* As = (u16*)pool;
    u16* Bs = (u16*)(pool + 16384);
    const int tid = threadIdx.x;
    const int bid = blockIdx.x;
    const int m0 = (bid / NY) * 128;
    const int n0 = (bid % NY) * 128;
    const int wid = tid >> 6, lane = tid & 63;
    const int wy = wid >> 1, wx = wid & 1;
    const int l15 = lane & 15, lsel = lane >> 4;

    f32x4 acc[4][4] = {};
    const u16* Ag = A + (size_t)m0 * KD;
    const u16* Bg = Bt + (size_t)n0 * KD;

    for (int k0 = 0; k0 < KD; k0 += 64) {
#pragma unroll
        for (int p = 0; p < 4; ++p) {               // 128 rows x 8 segs of 8 u16
            const int idx = p * 256 + tid;
            const int row = idx >> 3, s = idx & 7;
            const int so = (s ^ (row & 7)) << 3;    // source-preswizzled seg
            g2l16(Ag + (size_t)row * KD + k0 + so, As + idx * 8);
            g2l16(Bg + (size_t)row * KD + k0 + so, Bs + idx * 8);
        }
        __syncthreads();
#pragma unroll
        for (int kh = 0; kh < 2; ++kh) {
            bfrag8 af[4], bfv[4];
#pragma unroll
            for (int m = 0; m < 4; ++m) {
                const int r = wy * 64 + m * 16 + l15;
                af[m] = *(const bfrag8*)(As + r * 64 +
                         ((kh * 32 + lsel * 8) ^ ((r & 7) << 3)));
            }
#pragma unroll
            for (int n = 0; n < 4; ++n) {
                const int r = wx * 64 + n * 16 + l15;
                bfv[n] = *(const bfrag8*)(Bs + r * 64 +
                          ((kh * 32 + lsel * 8) ^ ((r & 7) << 3)));
            }
#pragma unroll
            for (int m = 0; m < 4; ++m)
#pragma unroll
                for (int n = 0; n < 4; ++n)
                    acc[m][n] = __builtin_amdgcn_mfma_f32_16x16x32_bf16(
                        af[m], bfv[n], acc[m][n], 0, 0, 0);
        }
        __syncthreads();
    }

    // ---------------- epilogue: per-wave LDS transpose ----------------
    float* Ts = (float*)pool + wid * (16 * 68);     // 4352 B per wave
    const int r  = lane >> 2;
    const int cg = (lane & 3) << 4;

#pragma unroll
    for (int m = 0; m < 4; ++m) {
#pragma unroll
        for (int n = 0; n < 4; ++n)
#pragma unroll
            for (int reg = 0; reg < 4; ++reg)
                Ts[(lsel * 4 + reg) * 68 + n * 16 + l15] = acc[m][n][reg];
        // wave-internal write->read: compiler inserts lgkmcnt wait
        float vals[16];
#pragma unroll
        for (int j = 0; j < 4; ++j)
            *(f32x4*)(vals + 4 * j) = *(const f32x4*)(Ts + r * 68 + cg + 4 * j);

        const int gr  = m0 + wy * 64 + m * 16 + r;
        const int gc0 = n0 + wx * 64 + cg;
        float bias16[16];
#pragma unroll
        for (int j = 0; j < 4; ++j)
            *(f32x4*)(bias16 + 4 * j) = *(const f32x4*)(bias + gc0 + 4 * j);

        if (EPI == 0) {
            const int win = gr / WS_TOK, tok = gr - win * WS_TOK;
            const int part = gc0 >> 8, head = (gc0 >> 5) & 7, hd = gc0 & 31;
            u16* dst = (part == 0) ? o0 : (part == 1) ? o1 : o2;
            const float sc = (part == 0) ? SCALE_Q : 1.f;
            const size_t di = (size_t)win * 8 * (WS_TOK * 32) + (size_t)tok * 32 +
                              (size_t)head * (WS_TOK * 32) + hd;
            u16x8 pk[2];
#pragma unroll
            for (int j = 0; j < 16; ++j)
                ((u16*)pk)[j] = f2u((vals[j] + bias16[j]) * sc);
            *(u16x8*)(dst + di)     = pk[0];
            *(u16x8*)(dst + di + 8) = pk[1];
        } else {
            const int win = gr / WS_TOK, tok = gr - win * WS_TOK;
            const int b_ = win >> 6, w64 = win & 63;
            const int wr = w64 >> 3, wc = w64 & 7;
            const int th = tok / 7, tw = tok - th * 7;
            int hh = wr * 7 + th + 3; if (hh >= 56) hh -= 56;  // roll(+3) scatter
            int ww = wc * 7 + tw + 3; if (ww >= 56) ww -= 56;
            const size_t di = ((size_t)b_ * 3136 + hh * 56 + ww) * C_DIM + gc0;
#pragma unroll
            for (int j = 0; j < 4; ++j) {
                f32x4 rr = *(const f32x4*)(res + di + 4 * j);
                f32x4 o;
#pragma unroll
                for (int e = 0; e < 4; ++e)
                    o[e] = rr[e] + vals[4 * j + e] + bias16[4 * j + e];
                *(f32x4*)(fo + di + 4 * j) = o;
            }
        }
    }
}

// --------------------------- fused MLP (R2-verified) -----------------------
// out += GELU(z @ w1T^T + b1) @ w2T^T + b2; h never leaves LDS.
// M-tile 64 rows, 4 waves (2x2). z persistent in LDS. Stage next 16KB tile
// into alternate buffer BEFORE the MFMAs, one __syncthreads per step.
// LDS 80KB -> 2 blocks/CU.
__device__ __forceinline__ void stage_w1t(const u16* __restrict__ w1T, u16* dst,
                                          int kc, int k0, int tid) {
#pragma unroll
    for (int p = 0; p < 4; ++p) {                   // [128 hcols][64 k] = 16KB
        const int i = p * 256 + tid;
        const int row = i >> 3, s = i & 7;
        g2l16(w1T + (size_t)(kc * 128 + row) * 256 + k0 + ((s ^ (row & 7)) << 3),
              dst + i * 8);
    }
}
__device__ __forceinline__ void stage_w2t(const u16* __restrict__ w2T, u16* dst,
                                          int kc, int bs, int tid) {
#pragma unroll
    for (int p = 0; p < 4; ++p) {                   // [256 outcols][32 k] = 16KB
        const int i = p * 256 + tid;
        const int row = i >> 2, s = i & 3;
        g2l16(w2T + (size_t)row * 1024 + kc * 128 + bs * 32 +
                  ((s ^ ((row >> 1) & 3)) << 3),
              dst + i * 8);
    }
}

__global__ __launch_bounds__(256, 2) void fused_mlp(const u16* __restrict__ z,
                                                    const u16* __restrict__ w1T,
                                                    const float* __restrict__ b1,
                                                    const u16* __restrict__ w2T,
                                                    const float* __restrict__ b2,
                                                    float* __restrict__ out) {
    __shared__ __align__(16) u16 pool[40960];       // 80 KB
    u16* zS  = pool;                                // [0,16384)  32 KB persistent
    u16* wb0 = pool + 16384;                        // 16 KB stage buffer A
    u16* wb1 = pool + 24576;                        // 16 KB stage buffer B
    u16* hc  = pool + 32768;                        // 16 KB h-chunk
    const int tid = threadIdx.x;
    const int wid = tid >> 6, lane = tid & 63;
    const int wy = wid >> 1, wx = wid & 1;
    const int l15 = lane & 15, lsel = lane >> 4;
    const int m0 = blockIdx.x * 64;

    // one-time z stage: [64 rows][256 k], source pre-swizzled (seg ^ row&7)
#pragma unroll
    for (int p = 0; p < 8; ++p) {
        const int i = p * 256 + tid;
        const int row = i >> 5, s = i & 31;
        g2l16(z + (size_t)(m0 + row) * 256 + ((s ^ (row & 7)) << 3), zS + i * 8);
    }
    stage_w1t(w1T, wb0, 0, 0, tid);                 // prologue: first w1 tile
    __syncthreads();

    f32x4 acc2[2][8] = {};

    for (int kc = 0; kc < 8; ++kc) {
        float b1v[4];
#pragma unroll
        for (int n = 0; n < 4; ++n)
            b1v[n] = b1[kc * 128 + wx * 64 + n * 16 + l15];

        f32x4 acc1[2][4] = {};
        // ---------------- 4 A-steps: acc1 += zS @ w1-tile -----------------
#pragma unroll
        for (int ks = 0; ks < 4; ++ks) {
            u16* wc = (ks & 1) ? wb1 : wb0;
            u16* wn = (ks & 1) ? wb0 : wb1;
            if (ks < 3) stage_w1t(w1T, wn, kc, (ks + 1) * 64, tid);
            else        stage_w2t(w2T, wn, kc, 0, tid);
#pragma unroll
            for (int sub = 0; sub < 2; ++sub) {
                bfrag8 af[2], bf[4];
#pragma unroll
                for (int m = 0; m < 2; ++m) {
                    const int r = wy * 32 + m * 16 + l15;
                    af[m] = *(const bfrag8*)(zS + r * 256 +
                             ((ks * 64 + sub * 32 + lsel * 8) ^ ((r & 7) << 3)));
                }
#pragma unroll
                for (int n = 0; n < 4; ++n) {
                    const int r = wx * 64 + n * 16 + l15;
                    bf[n] = *(const bfrag8*)(wc + r * 64 +
                             ((sub * 32 + lsel * 8) ^ ((r & 7) << 3)));
                }
#pragma unroll
                for (int m = 0; m < 2; ++m)
#pragma unroll
                    for (int n = 0; n < 4; ++n)
                        acc1[m][n] = __builtin_amdgcn_mfma_f32_16x16x32_bf16(
                            af[m], bf[n], acc1[m][n], 0, 0, 0);
            }
            if (ks == 3) {                          // GELU -> hc (swizzled bf16)
#pragma unroll
                for (int m = 0; m < 2; ++m)
#pragma unroll
                    for (int n = 0; n < 4; ++n)
#pragma unroll
                        for (int reg = 0; reg < 4; ++reg) {
                            const int rh = wy * 32 + m * 16 + lsel * 4 + reg;
                            const int ch = wx * 64 + n * 16 + l15;
                            hc[rh * 128 + (ch ^ ((rh & 15) << 3))] =
                                f2u(gelu_tanh(acc1[m][n][reg] + b1v[n]));
                        }
            }
            __syncthreads();
        }
        // ---------------- 4 B-steps: acc2 += hc @ w2-tile -----------------
#pragma unroll
        for (int bs = 0; bs < 4; ++bs) {
            u16* wc = (bs & 1) ? wb1 : wb0;
            u16* wn = (bs & 1) ? wb0 : wb1;
            if (bs < 3)      stage_w2t(w2T, wn, kc, bs + 1, tid);
            else if (kc < 7) stage_w1t(w1T, wn, kc + 1, 0, tid);
            bfrag8 a2[2], bb[8];
#pragma unroll
            for (int m = 0; m < 2; ++m) {
                const int r = wy * 32 + m * 16 + l15;
                a2[m] = *(const bfrag8*)(hc + r * 128 +
                         ((bs * 32 + lsel * 8) ^ ((r & 15) << 3)));
            }
#pragma unroll
            for (int n = 0; n < 8; ++n) {
                const int r = wx * 128 + n * 16 + l15;
                bb[n] = *(const bfrag8*)(wc + r * 32 +
                         ((lsel * 8) ^ (((r >> 1) & 3) << 3)));
            }
#pragma unroll
            for (int m = 0; m < 2; ++m)
#pragma unroll
                for (int n = 0; n < 8; ++n)
                    acc2[m][n] = __builtin_amdgcn_mfma_f32_16x16x32_bf16(
                        a2[m], bb[n], acc2[m][n], 0, 0, 0);
            __syncthreads();
        }
    }

    // ---------------- final epilogue: out += acc2 + b2 (in place) ---------
    float b2v[8];
#pragma unroll
    for (int n = 0; n < 8; ++n)
        b2v[n] = b2[wx * 128 + n * 16 + l15];
#pragma unroll
    for (int m = 0; m < 2; ++m)
#pragma unroll
        for (int reg = 0; reg < 4; ++reg) {
            const int row = m0 + wy * 32 + m * 16 + lsel * 4 + reg;
#pragma unroll
            for (int n = 0; n < 8; ++n) {
                const size_t di = (size_t)row * 256 + wx * 128 + n * 16 + l15;
                out[di] += acc2[m][n][reg] + b2v[n];
            }
        }
}

// ------------------------------ attention ----------------------------------
// 4 waves per 256-thread block, one (window,head) per wave, wave-private LDS
// (no barriers). 49 padded to 64. Vt and Pb XOR-swizzled (verified R7).
// V staging now vectorized: 16B bfrag8 global loads (4/lane, was 25 scalar
// 2B loads) + per-chunk ds_write scatter into the swizzled layout.
__global__ __launch_bounds__(256) void attn_kernel(const u16* __restrict__ q,
                                                   const u16* __restrict__ k,
                                                   const u16* __restrict__ v,
                                                   const float* __restrict__ relb,
                                                   u16* __restrict__ ao) {
    __shared__ __align__(16) u16 PbAll[4][64 * 64];
    __shared__ __align__(16) u16 VtAll[4][32 * 64];
    const int wid = threadIdx.x >> 6;
    const int lane = threadIdx.x & 63;
    u16* Pb = PbAll[wid];
    u16* Vt = VtAll[wid];
    const int bid = blockIdx.x * 4 + wid;
    const int head = bid & 7, win = bid >> 3;
    const int w64 = win & 63;
    const int wr = w64 >> 3, wc = w64 & 7;
    const int l15 = lane & 15, lsel = lane >> 4;
    const size_t base = (size_t)bid * (WS_TOK * 32);
    const u16* qb = q + base;
    const u16* kb = k + base;
    const u16* vb = v + base;

    // stage V transposed (vectorized): 196 chunks of 8 contiguous dims
    for (int c = lane; c < 196; c += 64) {
        const int tok = c >> 2, d0 = (c & 3) << 3;
        const bfrag8 v8 = *(const bfrag8*)(vb + tok * 32 + d0);
#pragma unroll
        for (int e = 0; e < 8; ++e)
            Vt[(d0 + e) * 64 + (tok ^ (e << 3))] = ((const u16*)&v8)[e];
    }
    for (int i = lane; i < 32 * 15; i += 64) {      // zero-pad tok 49..63
        const int dim = i / 15, tok = 49 + (i - dim * 15);
        Vt[dim * 64 + (tok ^ ((dim & 7) << 3))] = 0;
    }

    bfrag8 qf[4], kf[4];
#pragma unroll
    for (int m = 0; m < 4; ++m) {
        int tok = m * 16 + l15; if (tok > 48) tok = 48;
        qf[m] = *(const bfrag8*)(qb + tok * 32 + lsel * 8);
    }
#pragma unroll
    for (int n = 0; n < 4; ++n) {
        int tok = n * 16 + l15; if (tok > 48) tok = 48;
        kf[n] = *(const bfrag8*)(kb + tok * 32 + lsel * 8);
    }
    f32x4 S[4][4] = {};
#pragma unroll
    for (int m = 0; m < 4; ++m)
#pragma unroll
        for (int n = 0; n < 4; ++n)
            S[m][n] = __builtin_amdgcn_mfma_f32_16x16x32_bf16(qf[m], kf[n], S[m][n], 0, 0, 0);

    // bias + shift-mask + row softmax, write normalized P to LDS (swizzled)
#pragma unroll
    for (int m = 0; m < 4; ++m) {
#pragma unroll
        for (int reg = 0; reg < 4; ++reg) {
            const int row = m * 16 + lsel * 4 + reg;
            const int rowc = row > 48 ? 48 : row;
            const int ih = rowc / 7, iw = rowc - ih * 7;
            const int ri = regionOf(wr * 7 + ih) * 3 + regionOf(wc * 7 + iw);
            float sv[4];
#pragma unroll
            for (int n = 0; n < 4; ++n) {
                const int col = n * 16 + l15;
                float val = S[m][n][reg];
                if (col > 48) {
                    val = -1e30f;
                } else {
                    const int jh = col / 7, jw = col - jh * 7;
                    val += relb[((ih - jh + 6) * 13 + (iw - jw + 6)) * 8 + head];
                    const int rj = regionOf(wr * 7 + jh) * 3 + regionOf(wc * 7 + jw);
                    if (ri != rj) val -= 100.f;
                }
                sv[n] = val;
            }
            float mx = fmaxf(fmaxf(sv[0], sv[1]), fmaxf(sv[2], sv[3]));
#pragma unroll
            for (int off = 1; off < 16; off <<= 1) mx = fmaxf(mx, __shfl_xor(mx, off, 64));
            float p[4], sum = 0.f;
#pragma unroll
            for (int n = 0; n < 4; ++n) { p[n] = __expf(sv[n] - mx); sum += p[n]; }
#pragma unroll
            for (int off = 1; off < 16; off <<= 1) sum += __shfl_xor(sum, off, 64);
            const float inv = 1.f / sum;
#pragma unroll
            for (int n = 0; n < 4; ++n)
                Pb[row * 64 + ((n * 16 + l15) ^ ((row & 7) << 3))] = f2u(p[n] * inv);
        }
    }
    // wave-private LDS: no barrier needed

    // O = P V
    f32x4 O[4][2] = {};
    bfrag8 vf[2][2];
#pragma unroll
    for (int n = 0; n < 2; ++n) {
        const int r = n * 16 + l15;
        vf[n][0] = *(const bfrag8*)(Vt + r * 64 + ((lsel * 8) ^ ((r & 7) << 3)));
        vf[n][1] = *(const bfrag8*)(Vt + r * 64 + ((32 + lsel * 8) ^ ((r & 7) << 3)));
    }
#pragma unroll
    for (int m = 0; m < 4; ++m) {
        const int r = m * 16 + l15;
        const bfrag8 pf0 = *(const bfrag8*)(Pb + r * 64 +
                            ((lsel * 8) ^ ((r & 7) << 3)));
        const bfrag8 pf1 = *(const bfrag8*)(Pb + r * 64 +
                            ((32 + lsel * 8) ^ ((r & 7) << 3)));
#pragma unroll
        for (int n = 0; n < 2; ++n) {
            O[m][n] = __builtin_amdgcn_mfma_f32_16x16x32_bf16(pf0, vf[n][0], O[m][n], 0, 0, 0);
            O[m][n] = __builtin_amdgcn_mfma_f32_16x16x32_bf16(pf1, vf[n][1], O[m][n], 0, 0, 0);
        }
    }
    const size_t aob = (size_t)win * (WS_TOK * C_DIM) + head * 32;
#pragma unroll
    for (int m = 0; m < 4; ++m) {
#pragma unroll
        for (int reg = 0; reg < 4; ++reg) {
            const int row = m * 16 + lsel * 4 + reg;
            if (row < WS_TOK) {
#pragma unroll
                for (int n = 0; n < 2; ++n)
                    ao[aob + (size_t)row * C_DIM + n * 16 + l15] = f2u(O[m][n][reg]);
            }
        }
    }
}

// ------------------------------ launcher -----------------------------------
extern "C" void kernel_launch(void* const* d_in, const int* in_sizes, int n_in,
                              void* d_out, int out_size, void* d_ws, size_t ws_size,
                              hipStream_t stream) {
    (void)in_sizes; (void)n_in; (void)out_size; (void)ws_size;
    const float* x      = (const float*)d_in[0];
    const float* qkv_w  = (const float*)d_in[1];
    const float* qkv_b  = (const float*)d_in[2];
    const float* proj_w = (const float*)d_in[3];
    const float* proj_b = (const float*)d_in[4];
    const float* relb   = (const float*)d_in[5];
    const float* ln1g   = (const float*)d_in[6];
    const float* ln1b   = (const float*)d_in[7];
    const float* ln2g   = (const float*)d_in[8];
    const float* ln2b   = (const float*)d_in[9];
    const float* w1     = (const float*)d_in[10];
    const float* b1     = (const float*)d_in[11];
    const float* w2     = (const float*)d_in[12];
    const float* b2     = (const float*)d_in[13];
    float* out = (float*)d_out;

    const size_t SZ = (size_t)M_ROWS * C_DIM;      // 25,690,112 elements
    u16* wsu  = (u16*)d_ws;
    u16* xw   = wsu;                                // LN1-windowed input (bf16)
    u16* qq   = wsu + SZ;
    u16* kk   = wsu + 2 * SZ;
    u16* vv   = wsu + 3 * SZ;
    u16* ao   = wsu + 4 * SZ;
    u16* z    = xw;                                 // reuse (xw dead after QKV)
    u16* qkvT = wsu + 5 * SZ;
    u16* projT = qkvT + 256 * 768;
    u16* w1T  = projT + 256 * 256;
    u16* w2T  = w1T + 256 * 1024;

    transpose_all<<<3072, 256, 0, stream>>>(qkv_w, proj_w, w1, w2,
                                            qkvT, projT, w1T, w2T);

    ln_kernel<<<M_ROWS / 4, 256, 0, stream>>>(x, ln1g, ln1b, xw, 0);

    gemm_bt<256, 768, 6, 0><<<784 * 6, 256, 0, stream>>>(xw, qkvT, qkv_b,
                                                         qq, kk, vv, nullptr, nullptr);

    attn_kernel<<<N_WIN * 8 / 4, 256, 0, stream>>>(qq, kk, vv, relb, ao);

    gemm_bt<256, 256, 2, 1><<<784 * 2, 256, 0, stream>>>(ao, projT, proj_b,
                                                         nullptr, nullptr, nullptr, out, x);

    ln_kernel<<<M_ROWS / 4, 256, 0, stream>>>(out, ln2g, ln2b, z, 1);

    fused_mlp<<<M_ROWS / 64, 256, 0, stream>>>(z, w1T, b1, w2T, b2, out);
}